// Round 6
// baseline (289.981 us; speedup 1.0000x reference)
//
#include <hip/hip_runtime.h>
#include <hip/hip_bf16.h>

// SirenLinear: out[b,r] = sum_c x[b,c] * W[r,c] + bias[r]
//   W[r,c] = b3 + h2 . W3,  h2 = sin(30*(W2 h1 + b2)),  h1 = sin(30*(W1 e + b1))
//
// Round-12 (post-mortem r5: fused kernel 45us at 26% occupancy -- the 8192
// tiny cast blocks each reserve 12KB LDS and churn through the in-order
// dispatcher, starving CUs of siren blocks; only ~2 waves/SIMD resident while
// the siren chain (LDS->sin->MFMA->sin->DPP) is latency-bound. Bank conflicts
// are only ~4% -- not the issue):
//  * ONE block type: 2048 blocks (= 8/CU, LDS-limit exact). Each block does
//    its 16x32 siren tile AND 4 float4/thread of the x->bf16 cast, T14-style:
//    loads issued at kernel entry (latency hides under table staging + W2
//    preload), cvt+store before the barrier so cast regs die pre-compute.
//  * __launch_bounds__(256,8) pins VGPR<=64 -> 8 waves/SIMD truly resident.
//  * gemm + tables unchanged.

typedef __attribute__((ext_vector_type(8))) short bf16x8;
typedef __attribute__((ext_vector_type(4))) float f32x4;

#define SIN_SCALE 4.77464829275686f   // 30 / (2*pi)

__device__ __forceinline__ unsigned short f2bf(float f) {
    union { float f; unsigned u; } v; v.f = f;
    unsigned r = v.u + 0x7fffu + ((v.u >> 16) & 1u);   // RNE
    return (unsigned short)(r >> 16);
}

// pack 2 floats -> 2 bf16 by truncation (cheap; RNE kept for final store)
__device__ __forceinline__ unsigned pktrunc(float a, float b) {
    union { float f; unsigned u; } x, y; x.f = a; y.f = b;
    return (x.u >> 16) | (y.u & 0xffff0000u);
}

// sin(2*pi*x) -- raw v_sin_f32, valid |x| <= 256 revs (here |x| <= ~8.3)
__device__ __forceinline__ float sinrev(float x) {
    return __builtin_amdgcn_sinf(x);
}

// v += rotate_within_16lane_row(v, N)  -- DPP row_ror, pure VALU
template <int CTRL>
__device__ __forceinline__ float dpp_add(float v) {
    int r = __builtin_amdgcn_update_dpp(0, __float_as_int(v), CTRL, 0xf, 0xf, true);
    return v + __int_as_float(r);
}
// full 16-lane-row sum in every lane: ror 1,2,4,8
__device__ __forceinline__ float rowsum16(float v) {
    v = dpp_add<0x121>(v);   // row_ror:1
    v = dpp_add<0x122>(v);   // row_ror:2
    v = dpp_add<0x124>(v);   // row_ror:4
    v = dpp_add<0x128>(v);   // row_ror:8
    return v;
}

__device__ __forceinline__ void async_ld16(const void* g, void* l) {
    __builtin_amdgcn_global_load_lds(
        (__attribute__((address_space(1))) void*)g,
        (__attribute__((address_space(3))) void*)l, 16, 0, 0);
}

// ---------------- stage 0: layer-1 separable tables ----------------
// Zrow[r][j] = S*(W1[j,:].e(r,0)+b1[j]);  Zcol[c][j] = S*(W1[j,:].(e(0,c)-e(0,0)))
__global__ __launch_bounds__(256) void tables_kernel(
        const float* __restrict__ ec,
        const float* __restrict__ W1, const float* __restrict__ b1,
        float* __restrict__ Zrow, float* __restrict__ Zcol) {
    int idx = blockIdx.x * 256 + threadIdx.x;    // 0..131071
    int j = idx & 63;
    int t = idx >> 6;                            // 0..2047
    const float* wr = W1 + j * 18;
    if (t < 1024) {
        const float* pe = ec + (long)t * 1024 * 18;   // point (r=t, c=0)
        float z = b1[j];
        #pragma unroll
        for (int i = 0; i < 18; ++i) z += wr[i] * pe[i];
        Zrow[t * 64 + j] = SIN_SCALE * z;
    } else {
        int c = t - 1024;
        const float* pe = ec + (long)c * 18;          // point (r=0, c)
        float z = 0.f;
        #pragma unroll
        for (int i = 0; i < 18; ++i) z += wr[i] * (pe[i] - ec[i]);
        Zcol[c * 64 + j] = SIN_SCALE * z;
    }
}

// ---------------- stage 1: [generate W, LDS-tiled] + [x cast share] --------
// 2048 blocks, ALL identical: block sb covers W rows [br*16,+16) x cols
// [bc*32,+32) AND casts x float4s [(sb*4)*256, +1024) (4/thread, T14 split:
// load at entry, cvt+store before the barrier).
//
// siren: Zrow tile (4KB, linear) + Zcol tile (8KB, chunk-XOR-swizzled)
// staged once via global_load_lds (pre-swizzled source, m104/m173). Wave
// owns 4 rows; per row 2 col-tiles of 16. A-frag m=col(ln), k=kc*32+kq*8+j.
// C/D: col=ln (=n, h2 unit), row=kq*4+rg (=m, the col) [m89/m91]. Final
// 64-unit dot reduced with DPP rowsum16 (VALU, no DS latency).
__global__ __launch_bounds__(256, 8) void fused_cast_siren(
        const float4* __restrict__ x, unsigned short* __restrict__ xb,
        const float* __restrict__ Zrow, const float* __restrict__ Zcol,
        const float* __restrict__ W2, const float* __restrict__ b2,
        const float* __restrict__ W3, const float* __restrict__ b3,
        unsigned short* __restrict__ Wout) {
    __shared__ __align__(16) float zrow_l[16 * 64];   // 4 KB
    __shared__ __align__(16) float zcol_l[32 * 64];   // 8 KB, chunk-swizzled

    int tid  = threadIdx.x;
    int sb   = blockIdx.x;             // 0..2047
    int lane = tid & 63;
    int wv   = tid >> 6;
    int ln   = lane & 15;
    int kq   = lane >> 4;

    int br = sb & 63;                  // row-tile: rows [br*16, br*16+16)
    int bc = sb >> 6;                  // col-tile: cols [bc*32, bc*32+32)

    // ---- cast loads: issue FIRST (latency hides under staging + preload) ----
    long ci = (long)sb * 1024 + tid;
    float4 cv0 = x[ci];
    float4 cv1 = x[ci + 256];
    float4 cv2 = x[ci + 512];
    float4 cv3 = x[ci + 768];

    // ---- stage tables into LDS (3 x global_load_lds per thread) ----
    {
        const float* zr_src = Zrow + (long)br * 16 * 64 + (wv * 64 + lane) * 4;
        async_ld16(zr_src, zrow_l + wv * 256);        // linear, no swizzle
        #pragma unroll
        for (int half = 0; half < 2; ++half) {
            int P  = half * 256 + wv * 64 + lane;     // physical chunk 0..511
            int cr = P >> 4;                          // local col 0..31
            int lc = (P & 15) ^ (cr & 7);             // logical chunk to fetch
            const float* src = Zcol + (long)(bc * 32 + cr) * 64 + lc * 4;
            async_ld16(src, zcol_l + half * 1024 + wv * 256);
        }
    }

    // ---- cast cvt + store (regs die here, before the compute phase) ----
    {
        ushort4 o;
        o.x = f2bf(cv0.x); o.y = f2bf(cv0.y); o.z = f2bf(cv0.z); o.w = f2bf(cv0.w);
        *(ushort4*)(xb + ci * 4) = o;
        o.x = f2bf(cv1.x); o.y = f2bf(cv1.y); o.z = f2bf(cv1.z); o.w = f2bf(cv1.w);
        *(ushort4*)(xb + (ci + 256) * 4) = o;
        o.x = f2bf(cv2.x); o.y = f2bf(cv2.y); o.z = f2bf(cv2.z); o.w = f2bf(cv2.w);
        *(ushort4*)(xb + (ci + 512) * 4) = o;
        o.x = f2bf(cv3.x); o.y = f2bf(cv3.y); o.z = f2bf(cv3.z); o.w = f2bf(cv3.w);
        *(ushort4*)(xb + (ci + 768) * 4) = o;
    }

    // ---- preload B-frags of S*W2 (trunc bf16), S*b2, W3 ----
    bf16x8 bfrag[2][4];
    #pragma unroll
    for (int kc = 0; kc < 2; ++kc)
        #pragma unroll
        for (int nt = 0; nt < 4; ++nt) {
            const float* src = W2 + (nt * 16 + ln) * 64 + kc * 32 + kq * 8;
            union { bf16x8 v; unsigned u[4]; } tmp;
            #pragma unroll
            for (int q = 0; q < 4; ++q)
                tmp.u[q] = pktrunc(SIN_SCALE * src[2*q], SIN_SCALE * src[2*q + 1]);
            bfrag[kc][nt] = tmp.v;
        }
    float b2v[4], w3v[4];
    #pragma unroll
    for (int nt = 0; nt < 4; ++nt) {
        b2v[nt] = SIN_SCALE * b2[nt * 16 + ln];
        w3v[nt] = W3[nt * 16 + ln];
    }
    float b3s = b3[0];

    __syncthreads();                    // tables resident in LDS

    #pragma unroll
    for (int lr4 = 0; lr4 < 4; ++lr4) {
        int lr = wv * 4 + lr4;                         // local row 0..15
        const float* zb = zrow_l + lr * 64 + kq * 8;   // broadcast reads
        float zr0[8], zr1[8];
        #pragma unroll
        for (int j = 0; j < 8; ++j) { zr0[j] = zb[j]; zr1[j] = zb[32 + j]; }

        #pragma unroll
        for (int ct = 0; ct < 2; ++ct) {
            int cl = ct * 16 + ln;                     // local col 0..31
            const float* cb = zcol_l + cl * 64;
            int sw = cl & 7;
            float zc0[8], zc1[8];
            #pragma unroll
            for (int d = 0; d < 2; ++d) {
                int p0 = (((2 * kq + d)    ) ^ sw) * 4;
                int p1 = (((8 + 2 * kq + d)) ^ sw) * 4;
                #pragma unroll
                for (int e = 0; e < 4; ++e) {
                    zc0[d * 4 + e] = cb[p0 + e];
                    zc1[d * 4 + e] = cb[p1 + e];
                }
            }

            float s0[8], s1[8];
            #pragma unroll
            for (int j = 0; j < 8; ++j) {
                s0[j] = sinrev(zr0[j] + zc0[j]);
                s1[j] = sinrev(zr1[j] + zc1[j]);
            }
            union { bf16x8 v; unsigned u[4]; } a0, a1;
            #pragma unroll
            for (int q = 0; q < 4; ++q) {
                a0.u[q] = pktrunc(s0[2*q], s0[2*q + 1]);
                a1.u[q] = pktrunc(s1[2*q], s1[2*q + 1]);
            }

            f32x4 acc[4] = {};
            #pragma unroll
            for (int nt = 0; nt < 4; ++nt) {
                acc[nt] = __builtin_amdgcn_mfma_f32_16x16x32_bf16(a0.v, bfrag[0][nt], acc[nt], 0, 0, 0);
                acc[nt] = __builtin_amdgcn_mfma_f32_16x16x32_bf16(a1.v, bfrag[1][nt], acc[nt], 0, 0, 0);
            }

            float pa[4];
            #pragma unroll
            for (int rg = 0; rg < 4; ++rg) {
                float s = 0.f;
                #pragma unroll
                for (int nt = 0; nt < 4; ++nt)
                    s += w3v[nt] * sinrev(acc[nt][rg] + b2v[nt]);
                pa[rg] = rowsum16(s);                  // DPP, all-lane result
            }

            if (ln == 0) {               // 4 lanes (kq) store 4 cols each (RNE)
                long o = (long)(br * 16 + lr) * 1024 + bc * 32 + ct * 16 + kq * 4;
                ushort4 oa;
                oa.x = f2bf(pa[0] + b3s); oa.y = f2bf(pa[1] + b3s);
                oa.z = f2bf(pa[2] + b3s); oa.w = f2bf(pa[3] + b3s);
                *(ushort4*)(Wout + o) = oa;
            }
        }
    }
}

// ---------------- stage 2: out = x @ W^T + bias (bf16 MFMA) ----------------
// A = x_bf16 [8192][1024] K-contig; B = W_bf16 [1024][1024] (n=r, k=c) K-contig.
// Block: 256 thr = 4 waves (2x2 of 64x64), tile 128x128, BK=64.
// DOUBLE-BUFFERED: prefetch tile t+1 (global_load_lds) before computing tile
// t; single __syncthreads per tile. LDS 64KB -> 2 blocks/CU.
// Row = 128 B = 8 chunks of 16 B; stored position p holds logical chunk
// p ^ (row&7). Fragment reads hit all 8 positions -> 2 lanes/bank = free.
__global__ __launch_bounds__(256) void gemm_kernel(
        const unsigned short* __restrict__ A,
        const unsigned short* __restrict__ B,
        const float* __restrict__ bias,
        float* __restrict__ C) {
    const int K = 1024;
    __shared__ __align__(16) unsigned short As[2][128 * 64];
    __shared__ __align__(16) unsigned short Bs[2][128 * 64];

    int tid  = threadIdx.x;
    int lane = tid & 63;
    int wv   = tid >> 6;
    int wm   = wv & 1, wn = wv >> 1;
    long Abase = (long)blockIdx.x * 128 * K;
    long Bbase = (long)blockIdx.y * 128 * K;

    int sr8 = tid >> 3;     // staging row 0..31 (+32q)
    int sl  = tid & 7;      // staging chunk slot
    int rsel = lane & 15;   // fragment m/n within 16
    int kq   = lane >> 4;   // fragment k-quad 0..3

    f32x4 acc[4][4] = {};

    auto stage = [&](int kt, int sbuf) {
        #pragma unroll
        for (int q = 0; q < 4; ++q) {
            int row = q * 32 + sr8;
            int cc  = sl ^ (row & 7);                        // global chunk to fetch
            const unsigned short* ga = A + Abase + (long)row * K + kt + cc * 8;
            const unsigned short* gb = B + Bbase + (long)row * K + kt + cc * 8;
            unsigned short* la = &As[sbuf][(q * 256 + wv * 64) * 8];  // wave-uniform base
            unsigned short* lb = &Bs[sbuf][(q * 256 + wv * 64) * 8];
            async_ld16(ga, la);
            async_ld16(gb, lb);
        }
    };

    auto compute = [&](int sbuf) {
        #pragma unroll
        for (int h = 0; h < 2; ++h) {
            bf16x8 af[4], bf[4];
            #pragma unroll
            for (int mi = 0; mi < 4; ++mi) {
                int row = wm * 64 + mi * 16 + rsel;
                int ch  = (h * 4 + kq) ^ (row & 7);
                af[mi] = *(const bf16x8*)&As[sbuf][row * 64 + ch * 8];
            }
            #pragma unroll
            for (int ni = 0; ni < 4; ++ni) {
                int row = wn * 64 + ni * 16 + rsel;
                int ch  = (h * 4 + kq) ^ (row & 7);
                bf[ni] = *(const bf16x8*)&Bs[sbuf][row * 64 + ch * 8];
            }
            #pragma unroll
            for (int mi = 0; mi < 4; ++mi)
                #pragma unroll
                for (int ni = 0; ni < 4; ++ni)
                    acc[mi][ni] = __builtin_amdgcn_mfma_f32_16x16x32_bf16(
                        af[mi], bf[ni], acc[mi][ni], 0, 0, 0);
        }
    };

    stage(0, 0);
    __syncthreads();                 // drain prologue loads
    int buf = 0;
    for (int kt = 64; kt < K; kt += 64) {
        stage(kt, buf ^ 1);          // prefetch next tile (in flight across MFMAs)
        compute(buf);
        __syncthreads();             // all ds_reads of buf done + prefetch landed
        buf ^= 1;
    }
    compute(buf);                    // last tile, no further staging

    // epilogue: C/D layout col=lane&15, row=(lane>>4)*4+reg  (m89/m91 verified)
    int row0 = blockIdx.x * 128 + wm * 64;
    int col0 = blockIdx.y * 128 + wn * 64;
    #pragma unroll
    for (int ni = 0; ni < 4; ++ni) {
        int col = col0 + ni * 16 + rsel;
        float bv = bias[col];
        #pragma unroll
        for (int mi = 0; mi < 4; ++mi) {
            int rbase = row0 + mi * 16 + kq * 4;
            #pragma unroll
            for (int r = 0; r < 4; ++r)
                C[(long)(rbase + r) * 1024 + col] = acc[mi][ni][r] + bv;
        }
    }
}

extern "C" void kernel_launch(void* const* d_in, const int* in_sizes, int n_in,
                              void* d_out, int out_size, void* d_ws, size_t ws_size,
                              hipStream_t stream) {
    const float* x    = (const float*)d_in[0];
    const float* ec   = (const float*)d_in[1];
    const float* W1   = (const float*)d_in[2];
    const float* b1   = (const float*)d_in[3];
    const float* W2   = (const float*)d_in[4];
    const float* b2   = (const float*)d_in[5];
    const float* W3   = (const float*)d_in[6];
    const float* b3   = (const float*)d_in[7];
    const float* bias = (const float*)d_in[8];
    float* out = (float*)d_out;

    unsigned short* xb = (unsigned short*)d_ws;            // 8192*1024 bf16 = 16 MB
    unsigned short* Wb = xb + (size_t)8192 * 1024;         // 1024*1024 bf16 = 2 MB
    float* Zrow = (float*)(Wb + (size_t)1024 * 1024);      // 1024*64 f32 = 256 KB
    float* Zcol = Zrow + 1024 * 64;                        // 1024*64 f32 = 256 KB

    tables_kernel<<<512, 256, 0, stream>>>(ec, W1, b1, Zrow, Zcol);
    fused_cast_siren<<<2048, 256, 0, stream>>>((const float4*)x, xb, Zrow, Zcol,
                                               W2, b2, W3, b3, Wb);
    dim3 g(64, 8);
    gemm_kernel<<<g, 256, 0, stream>>>(xb, Wb, bias, out);
}

// Round 7
// 187.483 us; speedup vs baseline: 1.5467x; 1.5467x over previous
//
#include <hip/hip_runtime.h>
#include <hip/hip_bf16.h>

// SirenLinear: out[b,r] = sum_c x[b,c] * W[r,c] + bias[r]
//   W[r,c] = b3 + h2 . W3,  h2 = sin(30*(W2 h1 + b2)),  h1 = sin(30*(W1 e + b1))
//
// Round-13 (post-mortem r6: __launch_bounds__(256,8) forced VGPR=32 ->
// total spill, 470MB scratch traffic, 144us. BUT the uniform-block-type
// structure fixed occupancy 26->76% -- theory confirmed, cap was the bug):
//  * keep single block type (2048 blocks = 8/CU), DROP the VGPR cap
//    (launch_bounds(256,4), unconstraining -- same as r4's working siren).
//  * cast split in two 2-float4 halves (<=8 live regs): loads issued before
//    independent work (table staging / W2 preload), stores after (T14).
//  * tables + gemm unchanged from r5 (best wall 192.4).

typedef __attribute__((ext_vector_type(8))) short bf16x8;
typedef __attribute__((ext_vector_type(4))) float f32x4;

#define SIN_SCALE 4.77464829275686f   // 30 / (2*pi)

__device__ __forceinline__ unsigned short f2bf(float f) {
    union { float f; unsigned u; } v; v.f = f;
    unsigned r = v.u + 0x7fffu + ((v.u >> 16) & 1u);   // RNE
    return (unsigned short)(r >> 16);
}

// pack 2 floats -> 2 bf16 by truncation (cheap; RNE kept for final store)
__device__ __forceinline__ unsigned pktrunc(float a, float b) {
    union { float f; unsigned u; } x, y; x.f = a; y.f = b;
    return (x.u >> 16) | (y.u & 0xffff0000u);
}

// sin(2*pi*x) -- raw v_sin_f32, valid |x| <= 256 revs (here |x| <= ~8.3)
__device__ __forceinline__ float sinrev(float x) {
    return __builtin_amdgcn_sinf(x);
}

// v += rotate_within_16lane_row(v, N)  -- DPP row_ror, pure VALU
template <int CTRL>
__device__ __forceinline__ float dpp_add(float v) {
    int r = __builtin_amdgcn_update_dpp(0, __float_as_int(v), CTRL, 0xf, 0xf, true);
    return v + __int_as_float(r);
}
// full 16-lane-row sum in every lane: ror 1,2,4,8
__device__ __forceinline__ float rowsum16(float v) {
    v = dpp_add<0x121>(v);   // row_ror:1
    v = dpp_add<0x122>(v);   // row_ror:2
    v = dpp_add<0x124>(v);   // row_ror:4
    v = dpp_add<0x128>(v);   // row_ror:8
    return v;
}

__device__ __forceinline__ void async_ld16(const void* g, void* l) {
    __builtin_amdgcn_global_load_lds(
        (__attribute__((address_space(1))) void*)g,
        (__attribute__((address_space(3))) void*)l, 16, 0, 0);
}

// ---------------- stage 0: layer-1 separable tables ----------------
// Zrow[r][j] = S*(W1[j,:].e(r,0)+b1[j]);  Zcol[c][j] = S*(W1[j,:].(e(0,c)-e(0,0)))
__global__ __launch_bounds__(256) void tables_kernel(
        const float* __restrict__ ec,
        const float* __restrict__ W1, const float* __restrict__ b1,
        float* __restrict__ Zrow, float* __restrict__ Zcol) {
    int idx = blockIdx.x * 256 + threadIdx.x;    // 0..131071
    int j = idx & 63;
    int t = idx >> 6;                            // 0..2047
    const float* wr = W1 + j * 18;
    if (t < 1024) {
        const float* pe = ec + (long)t * 1024 * 18;   // point (r=t, c=0)
        float z = b1[j];
        #pragma unroll
        for (int i = 0; i < 18; ++i) z += wr[i] * pe[i];
        Zrow[t * 64 + j] = SIN_SCALE * z;
    } else {
        int c = t - 1024;
        const float* pe = ec + (long)c * 18;          // point (r=0, c)
        float z = 0.f;
        #pragma unroll
        for (int i = 0; i < 18; ++i) z += wr[i] * (pe[i] - ec[i]);
        Zcol[c * 64 + j] = SIN_SCALE * z;
    }
}

// ---------------- stage 1: [generate W, LDS-tiled] + [x cast share] --------
// 2048 blocks, ALL identical (uniform type -> 76% occupancy, r6 data):
// block sb covers W rows [br*16,+16) x cols [bc*32,+32) AND casts x float4s
// [sb*1024, +1024) (4/thread in two 2-float4 halves; loads issued before
// independent work, stores after -- T14, <=8 extra live VGPRs).
//
// siren: Zrow tile (4KB, linear) + Zcol tile (8KB, chunk-XOR-swizzled)
// staged once via global_load_lds (pre-swizzled source, m104/m173). Wave
// owns 4 rows; per row 2 col-tiles of 16. A-frag m=col(ln), k=kc*32+kq*8+j.
// C/D: col=ln (=n, h2 unit), row=kq*4+rg (=m, the col) [m89/m91]. Final
// 64-unit dot reduced with DPP rowsum16 (VALU, no DS latency).
__global__ __launch_bounds__(256, 4) void fused_cast_siren(
        const float4* __restrict__ x, unsigned short* __restrict__ xb,
        const float* __restrict__ Zrow, const float* __restrict__ Zcol,
        const float* __restrict__ W2, const float* __restrict__ b2,
        const float* __restrict__ W3, const float* __restrict__ b3,
        unsigned short* __restrict__ Wout) {
    __shared__ __align__(16) float zrow_l[16 * 64];   // 4 KB
    __shared__ __align__(16) float zcol_l[32 * 64];   // 8 KB, chunk-swizzled

    int tid  = threadIdx.x;
    int sb   = blockIdx.x;             // 0..2047
    int lane = tid & 63;
    int wv   = tid >> 6;
    int ln   = lane & 15;
    int kq   = lane >> 4;

    int br = sb & 63;                  // row-tile: rows [br*16, br*16+16)
    int bc = sb >> 6;                  // col-tile: cols [bc*32, bc*32+32)

    long ci = (long)sb * 1024 + tid;

    // ---- cast half 1: issue loads (latency hides under table staging) ----
    float4 cv0 = x[ci];
    float4 cv1 = x[ci + 256];

    // ---- stage tables into LDS (3 x global_load_lds per thread) ----
    {
        const float* zr_src = Zrow + (long)br * 16 * 64 + (wv * 64 + lane) * 4;
        async_ld16(zr_src, zrow_l + wv * 256);        // linear, no swizzle
        #pragma unroll
        for (int half = 0; half < 2; ++half) {
            int P  = half * 256 + wv * 64 + lane;     // physical chunk 0..511
            int cr = P >> 4;                          // local col 0..31
            int lc = (P & 15) ^ (cr & 7);             // logical chunk to fetch
            const float* src = Zcol + (long)(bc * 32 + cr) * 64 + lc * 4;
            async_ld16(src, zcol_l + half * 1024 + wv * 256);
        }
    }

    // ---- cast half 1: cvt + store; half 2: issue loads ----
    {
        ushort4 o;
        o.x = f2bf(cv0.x); o.y = f2bf(cv0.y); o.z = f2bf(cv0.z); o.w = f2bf(cv0.w);
        *(ushort4*)(xb + ci * 4) = o;
        o.x = f2bf(cv1.x); o.y = f2bf(cv1.y); o.z = f2bf(cv1.z); o.w = f2bf(cv1.w);
        *(ushort4*)(xb + (ci + 256) * 4) = o;
    }
    float4 cv2 = x[ci + 512];
    float4 cv3 = x[ci + 768];

    // ---- preload B-frags of S*W2 (trunc bf16), S*b2, W3 ----
    bf16x8 bfrag[2][4];
    #pragma unroll
    for (int kc = 0; kc < 2; ++kc)
        #pragma unroll
        for (int nt = 0; nt < 4; ++nt) {
            const float* src = W2 + (nt * 16 + ln) * 64 + kc * 32 + kq * 8;
            union { bf16x8 v; unsigned u[4]; } tmp;
            #pragma unroll
            for (int q = 0; q < 4; ++q)
                tmp.u[q] = pktrunc(SIN_SCALE * src[2*q], SIN_SCALE * src[2*q + 1]);
            bfrag[kc][nt] = tmp.v;
        }
    float b2v[4], w3v[4];
    #pragma unroll
    for (int nt = 0; nt < 4; ++nt) {
        b2v[nt] = SIN_SCALE * b2[nt * 16 + ln];
        w3v[nt] = W3[nt * 16 + ln];
    }
    float b3s = b3[0];

    // ---- cast half 2: cvt + store (regs die before compute phase) ----
    {
        ushort4 o;
        o.x = f2bf(cv2.x); o.y = f2bf(cv2.y); o.z = f2bf(cv2.z); o.w = f2bf(cv2.w);
        *(ushort4*)(xb + (ci + 512) * 4) = o;
        o.x = f2bf(cv3.x); o.y = f2bf(cv3.y); o.z = f2bf(cv3.z); o.w = f2bf(cv3.w);
        *(ushort4*)(xb + (ci + 768) * 4) = o;
    }

    __syncthreads();                    // tables resident in LDS

    #pragma unroll
    for (int lr4 = 0; lr4 < 4; ++lr4) {
        int lr = wv * 4 + lr4;                         // local row 0..15
        const float* zb = zrow_l + lr * 64 + kq * 8;   // broadcast reads
        float zr0[8], zr1[8];
        #pragma unroll
        for (int j = 0; j < 8; ++j) { zr0[j] = zb[j]; zr1[j] = zb[32 + j]; }

        #pragma unroll
        for (int ct = 0; ct < 2; ++ct) {
            int cl = ct * 16 + ln;                     // local col 0..31
            const float* cb = zcol_l + cl * 64;
            int sw = cl & 7;
            float zc0[8], zc1[8];
            #pragma unroll
            for (int d = 0; d < 2; ++d) {
                int p0 = (((2 * kq + d)    ) ^ sw) * 4;
                int p1 = (((8 + 2 * kq + d)) ^ sw) * 4;
                #pragma unroll
                for (int e = 0; e < 4; ++e) {
                    zc0[d * 4 + e] = cb[p0 + e];
                    zc1[d * 4 + e] = cb[p1 + e];
                }
            }

            float s0[8], s1[8];
            #pragma unroll
            for (int j = 0; j < 8; ++j) {
                s0[j] = sinrev(zr0[j] + zc0[j]);
                s1[j] = sinrev(zr1[j] + zc1[j]);
            }
            union { bf16x8 v; unsigned u[4]; } a0, a1;
            #pragma unroll
            for (int q = 0; q < 4; ++q) {
                a0.u[q] = pktrunc(s0[2*q], s0[2*q + 1]);
                a1.u[q] = pktrunc(s1[2*q], s1[2*q + 1]);
            }

            f32x4 acc[4] = {};
            #pragma unroll
            for (int nt = 0; nt < 4; ++nt) {
                acc[nt] = __builtin_amdgcn_mfma_f32_16x16x32_bf16(a0.v, bfrag[0][nt], acc[nt], 0, 0, 0);
                acc[nt] = __builtin_amdgcn_mfma_f32_16x16x32_bf16(a1.v, bfrag[1][nt], acc[nt], 0, 0, 0);
            }

            float pa[4];
            #pragma unroll
            for (int rg = 0; rg < 4; ++rg) {
                float s = 0.f;
                #pragma unroll
                for (int nt = 0; nt < 4; ++nt)
                    s += w3v[nt] * sinrev(acc[nt][rg] + b2v[nt]);
                pa[rg] = rowsum16(s);                  // DPP, all-lane result
            }

            if (ln == 0) {               // 4 lanes (kq) store 4 cols each (RNE)
                long o = (long)(br * 16 + lr) * 1024 + bc * 32 + ct * 16 + kq * 4;
                ushort4 oa;
                oa.x = f2bf(pa[0] + b3s); oa.y = f2bf(pa[1] + b3s);
                oa.z = f2bf(pa[2] + b3s); oa.w = f2bf(pa[3] + b3s);
                *(ushort4*)(Wout + o) = oa;
            }
        }
    }
}

// ---------------- stage 2: out = x @ W^T + bias (bf16 MFMA) ----------------
// A = x_bf16 [8192][1024] K-contig; B = W_bf16 [1024][1024] (n=r, k=c) K-contig.
// Block: 256 thr = 4 waves (2x2 of 64x64), tile 128x128, BK=64.
// DOUBLE-BUFFERED: prefetch tile t+1 (global_load_lds) before computing tile
// t; single __syncthreads per tile. LDS 64KB -> 2 blocks/CU.
// Row = 128 B = 8 chunks of 16 B; stored position p holds logical chunk
// p ^ (row&7). Fragment reads hit all 8 positions -> 2 lanes/bank = free.
__global__ __launch_bounds__(256) void gemm_kernel(
        const unsigned short* __restrict__ A,
        const unsigned short* __restrict__ B,
        const float* __restrict__ bias,
        float* __restrict__ C) {
    const int K = 1024;
    __shared__ __align__(16) unsigned short As[2][128 * 64];
    __shared__ __align__(16) unsigned short Bs[2][128 * 64];

    int tid  = threadIdx.x;
    int lane = tid & 63;
    int wv   = tid >> 6;
    int wm   = wv & 1, wn = wv >> 1;
    long Abase = (long)blockIdx.x * 128 * K;
    long Bbase = (long)blockIdx.y * 128 * K;

    int sr8 = tid >> 3;     // staging row 0..31 (+32q)
    int sl  = tid & 7;      // staging chunk slot
    int rsel = lane & 15;   // fragment m/n within 16
    int kq   = lane >> 4;   // fragment k-quad 0..3

    f32x4 acc[4][4] = {};

    auto stage = [&](int kt, int sbuf) {
        #pragma unroll
        for (int q = 0; q < 4; ++q) {
            int row = q * 32 + sr8;
            int cc  = sl ^ (row & 7);                        // global chunk to fetch
            const unsigned short* ga = A + Abase + (long)row * K + kt + cc * 8;
            const unsigned short* gb = B + Bbase + (long)row * K + kt + cc * 8;
            unsigned short* la = &As[sbuf][(q * 256 + wv * 64) * 8];  // wave-uniform base
            unsigned short* lb = &Bs[sbuf][(q * 256 + wv * 64) * 8];
            async_ld16(ga, la);
            async_ld16(gb, lb);
        }
    };

    auto compute = [&](int sbuf) {
        #pragma unroll
        for (int h = 0; h < 2; ++h) {
            bf16x8 af[4], bf[4];
            #pragma unroll
            for (int mi = 0; mi < 4; ++mi) {
                int row = wm * 64 + mi * 16 + rsel;
                int ch  = (h * 4 + kq) ^ (row & 7);
                af[mi] = *(const bf16x8*)&As[sbuf][row * 64 + ch * 8];
            }
            #pragma unroll
            for (int ni = 0; ni < 4; ++ni) {
                int row = wn * 64 + ni * 16 + rsel;
                int ch  = (h * 4 + kq) ^ (row & 7);
                bf[ni] = *(const bf16x8*)&Bs[sbuf][row * 64 + ch * 8];
            }
            #pragma unroll
            for (int mi = 0; mi < 4; ++mi)
                #pragma unroll
                for (int ni = 0; ni < 4; ++ni)
                    acc[mi][ni] = __builtin_amdgcn_mfma_f32_16x16x32_bf16(
                        af[mi], bf[ni], acc[mi][ni], 0, 0, 0);
        }
    };

    stage(0, 0);
    __syncthreads();                 // drain prologue loads
    int buf = 0;
    for (int kt = 64; kt < K; kt += 64) {
        stage(kt, buf ^ 1);          // prefetch next tile (in flight across MFMAs)
        compute(buf);
        __syncthreads();             // all ds_reads of buf done + prefetch landed
        buf ^= 1;
    }
    compute(buf);                    // last tile, no further staging

    // epilogue: C/D layout col=lane&15, row=(lane>>4)*4+reg  (m89/m91 verified)
    int row0 = blockIdx.x * 128 + wm * 64;
    int col0 = blockIdx.y * 128 + wn * 64;
    #pragma unroll
    for (int ni = 0; ni < 4; ++ni) {
        int col = col0 + ni * 16 + rsel;
        float bv = bias[col];
        #pragma unroll
        for (int mi = 0; mi < 4; ++mi) {
            int rbase = row0 + mi * 16 + kq * 4;
            #pragma unroll
            for (int r = 0; r < 4; ++r)
                C[(long)(rbase + r) * 1024 + col] = acc[mi][ni][r] + bv;
        }
    }
}

extern "C" void kernel_launch(void* const* d_in, const int* in_sizes, int n_in,
                              void* d_out, int out_size, void* d_ws, size_t ws_size,
                              hipStream_t stream) {
    const float* x    = (const float*)d_in[0];
    const float* ec   = (const float*)d_in[1];
    const float* W1   = (const float*)d_in[2];
    const float* b1   = (const float*)d_in[3];
    const float* W2   = (const float*)d_in[4];
    const float* b2   = (const float*)d_in[5];
    const float* W3   = (const float*)d_in[6];
    const float* b3   = (const float*)d_in[7];
    const float* bias = (const float*)d_in[8];
    float* out = (float*)d_out;

    unsigned short* xb = (unsigned short*)d_ws;            // 8192*1024 bf16 = 16 MB
    unsigned short* Wb = xb + (size_t)8192 * 1024;         // 1024*1024 bf16 = 2 MB
    float* Zrow = (float*)(Wb + (size_t)1024 * 1024);      // 1024*64 f32 = 256 KB
    float* Zcol = Zrow + 1024 * 64;                        // 1024*64 f32 = 256 KB

    tables_kernel<<<512, 256, 0, stream>>>(ec, W1, b1, Zrow, Zcol);
    fused_cast_siren<<<2048, 256, 0, stream>>>((const float4*)x, xb, Zrow, Zcol,
                                               W2, b2, W3, b3, Wb);
    dim3 g(64, 8);
    gemm_kernel<<<g, 256, 0, stream>>>(xb, Wb, bias, out);
}

// Round 8
// 183.182 us; speedup vs baseline: 1.5830x; 1.0235x over previous
//
#include <hip/hip_runtime.h>
#include <hip/hip_bf16.h>

// SirenLinear: out[b,r] = sum_c x[b,c] * W[r,c] + bias[r]
//   W[r,c] = b3 + h2 . W3,  h2 = sin(30*(W2 h1 + b2)),  h1 = sin(30*(W1 e + b1))
//
// Round-14 (post-mortem r7: fused ~40us by wall arithmetic; main-loop issue
// budget dominated by reduction bookkeeping: 16 b2-adds + 4x rowsum16 DPP
// chains + scattered 4-lane stores ~= 80/190 instrs per iter):
//  * MFMA operands SWAPPED: mfma(W2frag, h1frag, acc) -- same lane packing
//    for A and B frags (gemm-verified), so only the argument order changes.
//    C/D now: point=ln, unit=nt*16+kq*4+rg. This makes:
//      - b2 fold into acc INIT (float4 load, deletes 16 v_add/iter)
//      - W3 dot in-lane (16 fma) + 2 __shfl_xor(^32,^16) + 2 add
//        (replaces 4x rowsum16 = ~64 DPP ops/iter)
//      - store coalesced: 16 lanes (kq==0) x bf16 = one 32B masked store
//  * cast split, LDS staging, tables, gemm unchanged (isolate one theory).

typedef __attribute__((ext_vector_type(8))) short bf16x8;
typedef __attribute__((ext_vector_type(4))) float f32x4;

#define SIN_SCALE 4.77464829275686f   // 30 / (2*pi)

__device__ __forceinline__ unsigned short f2bf(float f) {
    union { float f; unsigned u; } v; v.f = f;
    unsigned r = v.u + 0x7fffu + ((v.u >> 16) & 1u);   // RNE
    return (unsigned short)(r >> 16);
}

// pack 2 floats -> 2 bf16 by truncation (cheap; RNE kept for final store)
__device__ __forceinline__ unsigned pktrunc(float a, float b) {
    union { float f; unsigned u; } x, y; x.f = a; y.f = b;
    return (x.u >> 16) | (y.u & 0xffff0000u);
}

// sin(2*pi*x) -- raw v_sin_f32, valid |x| <= 256 revs (here |x| <= ~8.3)
__device__ __forceinline__ float sinrev(float x) {
    return __builtin_amdgcn_sinf(x);
}

__device__ __forceinline__ void async_ld16(const void* g, void* l) {
    __builtin_amdgcn_global_load_lds(
        (__attribute__((address_space(1))) void*)g,
        (__attribute__((address_space(3))) void*)l, 16, 0, 0);
}

// ---------------- stage 0: layer-1 separable tables ----------------
// Zrow[r][j] = S*(W1[j,:].e(r,0)+b1[j]);  Zcol[c][j] = S*(W1[j,:].(e(0,c)-e(0,0)))
__global__ __launch_bounds__(256) void tables_kernel(
        const float* __restrict__ ec,
        const float* __restrict__ W1, const float* __restrict__ b1,
        float* __restrict__ Zrow, float* __restrict__ Zcol) {
    int idx = blockIdx.x * 256 + threadIdx.x;    // 0..131071
    int j = idx & 63;
    int t = idx >> 6;                            // 0..2047
    const float* wr = W1 + j * 18;
    if (t < 1024) {
        const float* pe = ec + (long)t * 1024 * 18;   // point (r=t, c=0)
        float z = b1[j];
        #pragma unroll
        for (int i = 0; i < 18; ++i) z += wr[i] * pe[i];
        Zrow[t * 64 + j] = SIN_SCALE * z;
    } else {
        int c = t - 1024;
        const float* pe = ec + (long)c * 18;          // point (r=0, c)
        float z = 0.f;
        #pragma unroll
        for (int i = 0; i < 18; ++i) z += wr[i] * (pe[i] - ec[i]);
        Zcol[c * 64 + j] = SIN_SCALE * z;
    }
}

// ---------------- stage 1: [generate W, LDS-tiled] + [x cast share] --------
// 2048 blocks, ALL identical (uniform type -> high occupancy, r6 data):
// block sb covers W rows [br*16,+16) x cols [bc*32,+32) AND casts x float4s
// [sb*1024, +1024) (4/thread in two 2-float4 halves; loads issued before
// independent work, stores after -- T14, <=8 extra live VGPRs).
//
// siren: Zrow tile (4KB, linear) + Zcol tile (8KB, chunk-XOR-swizzled)
// staged once via global_load_lds (pre-swizzled source, m104/m173). Wave
// owns 4 rows; per row 2 col-tiles of 16 points. h1 frag: lane ln = point,
// k = kc*32+kq*8+j (identical packing serves as the MFMA B operand).
// W2 frag (A operand): lane ln = unit-within-subtile. C/D [m89/m91]:
// n(col)=ln=point, m(row)=kq*4+rg=unit-within-subtile -> unit=nt*16+kq*4+rg.
// acc init = S*b2[unit]; layer-2: in-lane 16 sin+fma, then ^32/^16 shfl
// reduce over kq; kq==0 lanes store 16 contiguous bf16.
__global__ __launch_bounds__(256, 4) void fused_cast_siren(
        const float4* __restrict__ x, unsigned short* __restrict__ xb,
        const float* __restrict__ Zrow, const float* __restrict__ Zcol,
        const float* __restrict__ W2, const float* __restrict__ b2,
        const float* __restrict__ W3, const float* __restrict__ b3,
        unsigned short* __restrict__ Wout) {
    __shared__ __align__(16) float zrow_l[16 * 64];   // 4 KB
    __shared__ __align__(16) float zcol_l[32 * 64];   // 8 KB, chunk-swizzled

    int tid  = threadIdx.x;
    int sb   = blockIdx.x;             // 0..2047
    int lane = tid & 63;
    int wv   = tid >> 6;
    int ln   = lane & 15;
    int kq   = lane >> 4;

    int br = sb & 63;                  // row-tile: rows [br*16, br*16+16)
    int bc = sb >> 6;                  // col-tile: cols [bc*32, bc*32+32)

    long ci = (long)sb * 1024 + tid;

    // ---- cast half 1: issue loads (latency hides under table staging) ----
    float4 cv0 = x[ci];
    float4 cv1 = x[ci + 256];

    // ---- stage tables into LDS (3 x global_load_lds per thread) ----
    {
        const float* zr_src = Zrow + (long)br * 16 * 64 + (wv * 64 + lane) * 4;
        async_ld16(zr_src, zrow_l + wv * 256);        // linear, no swizzle
        #pragma unroll
        for (int half = 0; half < 2; ++half) {
            int P  = half * 256 + wv * 64 + lane;     // physical chunk 0..511
            int cr = P >> 4;                          // local col 0..31
            int lc = (P & 15) ^ (cr & 7);             // logical chunk to fetch
            const float* src = Zcol + (long)(bc * 32 + cr) * 64 + lc * 4;
            async_ld16(src, zcol_l + half * 1024 + wv * 256);
        }
    }

    // ---- cast half 1: cvt + store; half 2: issue loads ----
    {
        ushort4 o;
        o.x = f2bf(cv0.x); o.y = f2bf(cv0.y); o.z = f2bf(cv0.z); o.w = f2bf(cv0.w);
        *(ushort4*)(xb + ci * 4) = o;
        o.x = f2bf(cv1.x); o.y = f2bf(cv1.y); o.z = f2bf(cv1.z); o.w = f2bf(cv1.w);
        *(ushort4*)(xb + (ci + 256) * 4) = o;
    }
    float4 cv2 = x[ci + 512];
    float4 cv3 = x[ci + 768];

    // ---- preload A-frags of S*W2 (trunc bf16); S*b2 and W3 as float4 ----
    bf16x8 wfrag[2][4];
    #pragma unroll
    for (int kc = 0; kc < 2; ++kc)
        #pragma unroll
        for (int nt = 0; nt < 4; ++nt) {
            const float* src = W2 + (nt * 16 + ln) * 64 + kc * 32 + kq * 8;
            union { bf16x8 v; unsigned u[4]; } tmp;
            #pragma unroll
            for (int q = 0; q < 4; ++q)
                tmp.u[q] = pktrunc(SIN_SCALE * src[2*q], SIN_SCALE * src[2*q + 1]);
            wfrag[kc][nt] = tmp.v;
        }
    f32x4 b2x4[4], w3x4[4];
    #pragma unroll
    for (int nt = 0; nt < 4; ++nt) {
        float4 bb = *(const float4*)(b2 + nt * 16 + kq * 4);
        float4 ww = *(const float4*)(W3 + nt * 16 + kq * 4);
        b2x4[nt][0] = SIN_SCALE * bb.x; b2x4[nt][1] = SIN_SCALE * bb.y;
        b2x4[nt][2] = SIN_SCALE * bb.z; b2x4[nt][3] = SIN_SCALE * bb.w;
        w3x4[nt][0] = ww.x; w3x4[nt][1] = ww.y; w3x4[nt][2] = ww.z; w3x4[nt][3] = ww.w;
    }
    float b3s = b3[0];

    // ---- cast half 2: cvt + store (regs die before compute phase) ----
    {
        ushort4 o;
        o.x = f2bf(cv2.x); o.y = f2bf(cv2.y); o.z = f2bf(cv2.z); o.w = f2bf(cv2.w);
        *(ushort4*)(xb + (ci + 512) * 4) = o;
        o.x = f2bf(cv3.x); o.y = f2bf(cv3.y); o.z = f2bf(cv3.z); o.w = f2bf(cv3.w);
        *(ushort4*)(xb + (ci + 768) * 4) = o;
    }

    __syncthreads();                    // tables resident in LDS

    #pragma unroll
    for (int lr4 = 0; lr4 < 4; ++lr4) {
        int lr = wv * 4 + lr4;                         // local row 0..15
        const float* zb = zrow_l + lr * 64 + kq * 8;   // broadcast reads
        float zr0[8], zr1[8];
        #pragma unroll
        for (int j = 0; j < 8; ++j) { zr0[j] = zb[j]; zr1[j] = zb[32 + j]; }

        #pragma unroll
        for (int ct = 0; ct < 2; ++ct) {
            int cl = ct * 16 + ln;                     // local col 0..31
            const float* cb = zcol_l + cl * 64;
            int sw = cl & 7;
            float zc0[8], zc1[8];
            #pragma unroll
            for (int d = 0; d < 2; ++d) {
                int p0 = (((2 * kq + d)    ) ^ sw) * 4;
                int p1 = (((8 + 2 * kq + d)) ^ sw) * 4;
                #pragma unroll
                for (int e = 0; e < 4; ++e) {
                    zc0[d * 4 + e] = cb[p0 + e];
                    zc1[d * 4 + e] = cb[p1 + e];
                }
            }

            float s0[8], s1[8];
            #pragma unroll
            for (int j = 0; j < 8; ++j) {
                s0[j] = sinrev(zr0[j] + zc0[j]);
                s1[j] = sinrev(zr1[j] + zc1[j]);
            }
            union { bf16x8 v; unsigned u[4]; } a0, a1;
            #pragma unroll
            for (int q = 0; q < 4; ++q) {
                a0.u[q] = pktrunc(s0[2*q], s0[2*q + 1]);
                a1.u[q] = pktrunc(s1[2*q], s1[2*q + 1]);
            }

            // acc init = S*b2[unit]; D[m=unit-in-subtile, n=point]
            f32x4 acc[4];
            #pragma unroll
            for (int nt = 0; nt < 4; ++nt) acc[nt] = b2x4[nt];
            #pragma unroll
            for (int nt = 0; nt < 4; ++nt) {
                acc[nt] = __builtin_amdgcn_mfma_f32_16x16x32_bf16(wfrag[0][nt], a0.v, acc[nt], 0, 0, 0);
                acc[nt] = __builtin_amdgcn_mfma_f32_16x16x32_bf16(wfrag[1][nt], a1.v, acc[nt], 0, 0, 0);
            }

            // layer-2: in-lane 16 sin+fma, then reduce over kq quarters
            float s = 0.f;
            #pragma unroll
            for (int nt = 0; nt < 4; ++nt)
                #pragma unroll
                for (int rg = 0; rg < 4; ++rg)
                    s = fmaf(w3x4[nt][rg], sinrev(acc[nt][rg]), s);
            s += __shfl_xor(s, 32, 64);
            s += __shfl_xor(s, 16, 64);

            if (kq == 0) {               // 16 lanes store 16 contiguous bf16
                long o = (long)(br * 16 + lr) * 1024 + bc * 32 + ct * 16 + ln;
                Wout[o] = f2bf(s + b3s);
            }
        }
    }
}

// ---------------- stage 2: out = x @ W^T + bias (bf16 MFMA) ----------------
// A = x_bf16 [8192][1024] K-contig; B = W_bf16 [1024][1024] (n=r, k=c) K-contig.
// Block: 256 thr = 4 waves (2x2 of 64x64), tile 128x128, BK=64.
// DOUBLE-BUFFERED: prefetch tile t+1 (global_load_lds) before computing tile
// t; single __syncthreads per tile. LDS 64KB -> 2 blocks/CU.
// Row = 128 B = 8 chunks of 16 B; stored position p holds logical chunk
// p ^ (row&7). Fragment reads hit all 8 positions -> 2 lanes/bank = free.
__global__ __launch_bounds__(256) void gemm_kernel(
        const unsigned short* __restrict__ A,
        const unsigned short* __restrict__ B,
        const float* __restrict__ bias,
        float* __restrict__ C) {
    const int K = 1024;
    __shared__ __align__(16) unsigned short As[2][128 * 64];
    __shared__ __align__(16) unsigned short Bs[2][128 * 64];

    int tid  = threadIdx.x;
    int lane = tid & 63;
    int wv   = tid >> 6;
    int wm   = wv & 1, wn = wv >> 1;
    long Abase = (long)blockIdx.x * 128 * K;
    long Bbase = (long)blockIdx.y * 128 * K;

    int sr8 = tid >> 3;     // staging row 0..31 (+32q)
    int sl  = tid & 7;      // staging chunk slot
    int rsel = lane & 15;   // fragment m/n within 16
    int kq   = lane >> 4;   // fragment k-quad 0..3

    f32x4 acc[4][4] = {};

    auto stage = [&](int kt, int sbuf) {
        #pragma unroll
        for (int q = 0; q < 4; ++q) {
            int row = q * 32 + sr8;
            int cc  = sl ^ (row & 7);                        // global chunk to fetch
            const unsigned short* ga = A + Abase + (long)row * K + kt + cc * 8;
            const unsigned short* gb = B + Bbase + (long)row * K + kt + cc * 8;
            unsigned short* la = &As[sbuf][(q * 256 + wv * 64) * 8];  // wave-uniform base
            unsigned short* lb = &Bs[sbuf][(q * 256 + wv * 64) * 8];
            async_ld16(ga, la);
            async_ld16(gb, lb);
        }
    };

    auto compute = [&](int sbuf) {
        #pragma unroll
        for (int h = 0; h < 2; ++h) {
            bf16x8 af[4], bf[4];
            #pragma unroll
            for (int mi = 0; mi < 4; ++mi) {
                int row = wm * 64 + mi * 16 + rsel;
                int ch  = (h * 4 + kq) ^ (row & 7);
                af[mi] = *(const bf16x8*)&As[sbuf][row * 64 + ch * 8];
            }
            #pragma unroll
            for (int ni = 0; ni < 4; ++ni) {
                int row = wn * 64 + ni * 16 + rsel;
                int ch  = (h * 4 + kq) ^ (row & 7);
                bf[ni] = *(const bf16x8*)&Bs[sbuf][row * 64 + ch * 8];
            }
            #pragma unroll
            for (int mi = 0; mi < 4; ++mi)
                #pragma unroll
                for (int ni = 0; ni < 4; ++ni)
                    acc[mi][ni] = __builtin_amdgcn_mfma_f32_16x16x32_bf16(
                        af[mi], bf[ni], acc[mi][ni], 0, 0, 0);
        }
    };

    stage(0, 0);
    __syncthreads();                 // drain prologue loads
    int buf = 0;
    for (int kt = 64; kt < K; kt += 64) {
        stage(kt, buf ^ 1);          // prefetch next tile (in flight across MFMAs)
        compute(buf);
        __syncthreads();             // all ds_reads of buf done + prefetch landed
        buf ^= 1;
    }
    compute(buf);                    // last tile, no further staging

    // epilogue: C/D layout col=lane&15, row=(lane>>4)*4+reg  (m89/m91 verified)
    int row0 = blockIdx.x * 128 + wm * 64;
    int col0 = blockIdx.y * 128 + wn * 64;
    #pragma unroll
    for (int ni = 0; ni < 4; ++ni) {
        int col = col0 + ni * 16 + rsel;
        float bv = bias[col];
        #pragma unroll
        for (int mi = 0; mi < 4; ++mi) {
            int rbase = row0 + mi * 16 + kq * 4;
            #pragma unroll
            for (int r = 0; r < 4; ++r)
                C[(long)(rbase + r) * 1024 + col] = acc[mi][ni][r] + bv;
        }
    }
}

extern "C" void kernel_launch(void* const* d_in, const int* in_sizes, int n_in,
                              void* d_out, int out_size, void* d_ws, size_t ws_size,
                              hipStream_t stream) {
    const float* x    = (const float*)d_in[0];
    const float* ec   = (const float*)d_in[1];
    const float* W1   = (const float*)d_in[2];
    const float* b1   = (const float*)d_in[3];
    const float* W2   = (const float*)d_in[4];
    const float* b2   = (const float*)d_in[5];
    const float* W3   = (const float*)d_in[6];
    const float* b3   = (const float*)d_in[7];
    const float* bias = (const float*)d_in[8];
    float* out = (float*)d_out;

    unsigned short* xb = (unsigned short*)d_ws;            // 8192*1024 bf16 = 16 MB
    unsigned short* Wb = xb + (size_t)8192 * 1024;         // 1024*1024 bf16 = 2 MB
    float* Zrow = (float*)(Wb + (size_t)1024 * 1024);      // 1024*64 f32 = 256 KB
    float* Zcol = Zrow + 1024 * 64;                        // 1024*64 f32 = 256 KB

    tables_kernel<<<512, 256, 0, stream>>>(ec, W1, b1, Zrow, Zcol);
    fused_cast_siren<<<2048, 256, 0, stream>>>((const float4*)x, xb, Zrow, Zcol,
                                               W2, b2, W3, b3, Wb);
    dim3 g(64, 8);
    gemm_kernel<<<g, 256, 0, stream>>>(xb, Wb, bias, out);
}